// Round 1
// baseline (2882.620 us; speedup 1.0000x reference)
//
#include <hip/hip_runtime.h>

typedef unsigned int uint;
typedef uint4 uint4_a __attribute__((may_alias));

// ---------- bf16 helpers ----------
__device__ __forceinline__ uint bfpack(float a, float b) {
  uint ua = __float_as_uint(a), ub = __float_as_uint(b);
  ua += 0x7fffu + ((ua >> 16) & 1u);   // RNE to bf16
  ub += 0x7fffu + ((ub >> 16) & 1u);
  return (ua >> 16) | (ub & 0xffff0000u);
}
__device__ __forceinline__ float bflo(uint d) { return __uint_as_float(d << 16); }
__device__ __forceinline__ float bfhi(uint d) { return __uint_as_float(d & 0xffff0000u); }

#if __has_builtin(__builtin_amdgcn_fdot2_f32_bf16)
#define HAVE_BFDOT 1
typedef __bf16 v2bf __attribute__((ext_vector_type(2)));
__device__ __forceinline__ float dot2bf(uint a, uint b, float c) {
  return __builtin_amdgcn_fdot2_f32_bf16(__builtin_bit_cast(v2bf, a),
                                         __builtin_bit_cast(v2bf, b), c, false);
}
#else
#define HAVE_BFDOT 0
#endif

// ---------- K1: transition table ----------
// Tcol[c*64 + j] = bf16x2( exp(tran[2j][c]), exp(tran[2j+1][c]) ), tran = log_softmax rows
__global__ void k_tran(const float* __restrict__ w, uint* __restrict__ Tcol) {
  __shared__ float rowLSE[128];
  int tid = threadIdx.x;                       // 128 threads
  const float4* w4 = (const float4*)(w + tid * 128);
  float se = 0.f;
  #pragma unroll 8
  for (int i = 0; i < 32; ++i) {
    float4 v = w4[i];
    se += __expf(v.x) + __expf(v.y) + __expf(v.z) + __expf(v.w);
  }
  rowLSE[tid] = __logf(se);                    // logits in (-1,1): shift-free LSE is exact enough
  __syncthreads();
  int c = tid;
  for (int j = 0; j < 64; ++j) {
    float a = __expf(w[(2 * j) * 128 + c]     - rowLSE[2 * j]);
    float b = __expf(w[(2 * j + 1) * 128 + c] - rowLSE[2 * j + 1]);
    Tcol[c * 64 + j] = bfpack(a, b);
  }
}

// ---------- K2a: logits (bf16, pair layout) + per-k sum of exp(logit) ----------
__global__ __launch_bounds__(256) void k_logits(const float* __restrict__ emb,
    const float* __restrict__ vocab, uint* __restrict__ qtbl,
    float* __restrict__ S_glob, int V) {
  __shared__ float S_part[128];
  int tid = threadIdx.x;
  int kt = tid & 15, vt = tid >> 4;
  int k0 = kt * 8;
  int vbase = blockIdx.x * 64 + vt * 4;
  if (tid < 128) S_part[tid] = 0.f;
  __syncthreads();

  float acc[4][8];
  #pragma unroll
  for (int i = 0; i < 4; ++i)
    #pragma unroll
    for (int r = 0; r < 8; ++r) acc[i][r] = 0.f;

  int vidx[4];
  #pragma unroll
  for (int i = 0; i < 4; ++i) { int vv = vbase + i; vidx[i] = (vv < V) ? vv : (V - 1); }

  const float4* emb4 = (const float4*)emb;
  const float4* voc4 = (const float4*)vocab;
  for (int jb = 0; jb < 32; ++jb) {
    float4 e4[8];
    #pragma unroll
    for (int r = 0; r < 8; ++r) e4[r] = emb4[(k0 + r) * 32 + jb];
    #pragma unroll
    for (int i = 0; i < 4; ++i) {
      float4 va = voc4[(size_t)vidx[i] * 32 + jb];
      #pragma unroll
      for (int r = 0; r < 8; ++r)
        acc[i][r] += va.x * e4[r].x + va.y * e4[r].y + va.z * e4[r].z + va.w * e4[r].w;
    }
  }

  float sume[8];
  #pragma unroll
  for (int r = 0; r < 8; ++r) sume[r] = 0.f;
  #pragma unroll
  for (int i = 0; i < 4; ++i) {
    int vv = vbase + i;
    if (vv < V) {
      #pragma unroll
      for (int r = 0; r < 8; ++r) sume[r] += __expf(acc[i][r]);   // |logit| <~ 40 : safe
      uint4 st;
      st.x = bfpack(acc[i][0], acc[i][1]);
      st.y = bfpack(acc[i][2], acc[i][3]);
      st.z = bfpack(acc[i][4], acc[i][5]);
      st.w = bfpack(acc[i][6], acc[i][7]);
      *((uint4*)(qtbl + (size_t)vv * 64) + kt) = st;
    }
  }
  #pragma unroll
  for (int r = 0; r < 8; ++r) atomicAdd(&S_part[k0 + r], sume[r]);
  __syncthreads();
  if (tid < 128) atomicAdd(&S_glob[tid], S_part[tid]);
}

// ---------- K2c: in-place q[v][k] = exp(emis - Emax_v) (bf16), Emax table ----------
__global__ __launch_bounds__(256) void k_qtab(uint* __restrict__ qtbl,
    const float* __restrict__ S_glob, float* __restrict__ Emax, int V) {
  int tid = threadIdx.x;
  int l = tid & 63;
  int v = blockIdx.x * 4 + (tid >> 6);
  if (v >= V) return;
  float2 S2 = ((const float2*)S_glob)[l];
  float z0 = __logf(S2.x), z1 = __logf(S2.y);
  size_t off = (size_t)v * 64 + l;
  uint d = qtbl[off];
  float e0 = bflo(d) - z0, e1 = bfhi(d) - z1;
  float m = fmaxf(e0, e1);
  #pragma unroll
  for (int s = 1; s < 64; s <<= 1) m = fmaxf(m, __shfl_xor(m, s, 64));
  float q0 = __expf(e0 - m), q1 = __expf(e1 - m);
  qtbl[off] = bfpack(q0, q1);
  if (l == 0) Emax[v] = m;
}

// ---------- K3: the sequential scan. One wave per chain. ----------
__global__ __launch_bounds__(64, 1) void k_chain(const int* __restrict__ x,
    const float* __restrict__ start_w, const float* __restrict__ start_b,
    const uint* __restrict__ Tcol, const uint* __restrict__ qtbl,
    float* __restrict__ chainLL) {
  __shared__ int xs[4096];
  __shared__ uint u_mem[64] __attribute__((aligned(16)));
  int n = blockIdx.x, l = threadIdx.x;
  const int* xrow = x + (size_t)n * 4096;
  #pragma unroll 4
  for (int i = l; i < 4096; i += 64) xs[i] = xrow[i];

#if HAVE_BFDOT
  uint T0[64], T1[64];
  {
    const uint4* c0 = (const uint4*)(Tcol + (2 * l) * 64);
    const uint4* c1 = (const uint4*)(Tcol + (2 * l + 1) * 64);
    #pragma unroll
    for (int i = 0; i < 16; ++i) {
      uint4 a = c0[i]; T0[4*i] = a.x; T0[4*i+1] = a.y; T0[4*i+2] = a.z; T0[4*i+3] = a.w;
      uint4 b = c1[i]; T1[4*i] = b.x; T1[4*i+1] = b.y; T1[4*i+2] = b.z; T1[4*i+3] = b.w;
    }
  }
#else
  float T0f[128], T1f[128];
  {
    const uint4* c0 = (const uint4*)(Tcol + (2 * l) * 64);
    const uint4* c1 = (const uint4*)(Tcol + (2 * l + 1) * 64);
    #pragma unroll
    for (int i = 0; i < 16; ++i) {
      uint4 a = c0[i];
      T0f[8*i+0] = bflo(a.x); T0f[8*i+1] = bfhi(a.x); T0f[8*i+2] = bflo(a.y); T0f[8*i+3] = bfhi(a.y);
      T0f[8*i+4] = bflo(a.z); T0f[8*i+5] = bfhi(a.z); T0f[8*i+6] = bflo(a.w); T0f[8*i+7] = bfhi(a.w);
      uint4 b = c1[i];
      T1f[8*i+0] = bflo(b.x); T1f[8*i+1] = bfhi(b.x); T1f[8*i+2] = bflo(b.y); T1f[8*i+3] = bfhi(b.y);
      T1f[8*i+4] = bflo(b.z); T1f[8*i+5] = bfhi(b.z); T1f[8*i+6] = bflo(b.w); T1f[8*i+7] = bfhi(b.w);
    }
  }
#endif

  // init: u0 = softmax(start_w + start_b), C0 = LSE(alpha0)
  float a0 = start_w[2 * l] + start_b[2 * l];
  float a1 = start_w[2 * l + 1] + start_b[2 * l + 1];
  float m = fmaxf(a0, a1);
  #pragma unroll
  for (int s = 1; s < 64; s <<= 1) m = fmaxf(m, __shfl_xor(m, s, 64));
  float p0 = __expf(a0 - m), p1 = __expf(a1 - m);
  float tot = p0 + p1;
  #pragma unroll
  for (int s = 1; s < 64; s <<= 1) tot += __shfl_xor(tot, s, 64);
  float LLacc = m + __logf(tot);
  float inv = 1.0f / tot;
  __syncthreads();
  u_mem[l] = bfpack(p0 * inv, p1 * inv);

  uint q_pf[8];
  #pragma unroll
  for (int j = 0; j < 8; ++j) q_pf[j] = qtbl[(size_t)xs[j] * 64 + l];

  const uint4_a* u4 = (const uint4_a*)u_mem;
  for (int t8 = 0; t8 < 512; ++t8) {
    #pragma unroll
    for (int j = 0; j < 8; ++j) {
      int t = t8 * 8 + j;
      float A0 = 0.f, A1 = 0.f, A2 = 0.f, A3 = 0.f;
      float B0 = 0.f, B1 = 0.f, B2 = 0.f, B3 = 0.f;
#if HAVE_BFDOT
      #pragma unroll
      for (int i = 0; i < 16; ++i) {
        uint4 uu = u4[i];
        A0 = dot2bf(uu.x, T0[4*i+0], A0); B0 = dot2bf(uu.x, T1[4*i+0], B0);
        A1 = dot2bf(uu.y, T0[4*i+1], A1); B1 = dot2bf(uu.y, T1[4*i+1], B1);
        A2 = dot2bf(uu.z, T0[4*i+2], A2); B2 = dot2bf(uu.z, T1[4*i+2], B2);
        A3 = dot2bf(uu.w, T0[4*i+3], A3); B3 = dot2bf(uu.w, T1[4*i+3], B3);
      }
#else
      #pragma unroll
      for (int i = 0; i < 16; ++i) {
        uint4 uu = u4[i];
        float x0 = bflo(uu.x), x1 = bfhi(uu.x), x2 = bflo(uu.y), x3 = bfhi(uu.y);
        float x4 = bflo(uu.z), x5 = bfhi(uu.z), x6 = bflo(uu.w), x7 = bfhi(uu.w);
        A0 += x0 * T0f[8*i+0]; B0 += x0 * T1f[8*i+0];
        A1 += x1 * T0f[8*i+1]; B1 += x1 * T1f[8*i+1];
        A2 += x2 * T0f[8*i+2]; B2 += x2 * T1f[8*i+2];
        A3 += x3 * T0f[8*i+3]; B3 += x3 * T1f[8*i+3];
        A0 += x4 * T0f[8*i+4]; B0 += x4 * T1f[8*i+4];
        A1 += x5 * T0f[8*i+5]; B1 += x5 * T1f[8*i+5];
        A2 += x6 * T0f[8*i+6]; B2 += x6 * T1f[8*i+6];
        A3 += x7 * T0f[8*i+7]; B3 += x7 * T1f[8*i+7];
      }
#endif
      float s0 = (A0 + A1) + (A2 + A3);
      float s1 = (B0 + B1) + (B2 + B3);
      uint qd = q_pf[j];
      float nu0 = s0 * bflo(qd), nu1 = s1 * bfhi(qd);
      int wn = xs[(t + 8) & 4095];
      q_pf[j] = qtbl[(size_t)wn * 64 + l];          // prefetch 8 steps ahead
      if (j == 7) {                                  // exact renorm every 8 steps
        float tt = nu0 + nu1;
        #pragma unroll
        for (int s = 1; s < 64; s <<= 1) tt += __shfl_xor(tt, s, 64);
        LLacc += __logf(tt);
        float it = 1.0f / tt;
        nu0 *= it; nu1 *= it;
      }
      u_mem[l] = bfpack(nu0, nu1);                   // wave-lockstep: no barrier needed
    }
  }
  if (l == 0) chainLL[n] = LLacc;
}

// ---------- K4a: sum of Emax over all tokens ----------
__global__ __launch_bounds__(256) void k_emaxsum(const int* __restrict__ x,
    const float* __restrict__ Emax, float* __restrict__ sumE, int NT) {
  int idx = blockIdx.x * 256 + threadIdx.x;
  float s = 0.f;
  for (; idx < NT; idx += 128 * 256) s += Emax[x[idx]];
  #pragma unroll
  for (int mk = 1; mk < 64; mk <<= 1) s += __shfl_xor(s, mk, 64);
  if ((threadIdx.x & 63) == 0) atomicAdd(sumE, s);
}

// ---------- K4b: final scalar ----------
__global__ void k_final(const float* __restrict__ chainLL, const float* __restrict__ sumE,
                        float* __restrict__ out, int N) {
  int l = threadIdx.x;
  float v = (l < N) ? chainLL[l] : 0.f;
  #pragma unroll
  for (int mk = 1; mk < 64; mk <<= 1) v += __shfl_xor(v, mk, 64);
  if (l == 0) out[0] = -(v + sumE[0]) / (float)N;
}

extern "C" void kernel_launch(void* const* d_in, const int* in_sizes, int n_in,
                              void* d_out, int out_size, void* d_ws, size_t ws_size,
                              hipStream_t stream) {
  if (n_in < 6) return;
  const int*   x       = (const int*)d_in[0];
  const float* start_w = (const float*)d_in[1];
  const float* start_b = (const float*)d_in[2];
  const float* trans_w = (const float*)d_in[3];
  const float* emb_w   = (const float*)d_in[4];
  const float* vocab_w = (const float*)d_in[5];
  int NT = in_sizes[0];
  int N  = NT / 4096;
  int V  = in_sizes[5] / 128;

  char* ws = (char*)d_ws;
  float* S_glob  = (float*)(ws + 0);        // 128 f
  float* sumE    = (float*)(ws + 512);      // 1 f
  float* chainLL = (float*)(ws + 768);      // N f
  uint*  Tcol    = (uint*)(ws + 1024);      // 128*64 dwords = 32 KB
  float* Emax    = (float*)(ws + 36864);    // V floats
  uint*  qtbl    = (uint*)(ws + 262144);    // V*64 dwords = 12.8 MB

  hipMemsetAsync(d_ws, 0, 1024, stream);
  k_tran<<<dim3(1), dim3(128), 0, stream>>>(trans_w, Tcol);
  k_logits<<<dim3((V + 63) / 64), dim3(256), 0, stream>>>(emb_w, vocab_w, qtbl, S_glob, V);
  k_qtab<<<dim3((V + 3) / 4), dim3(256), 0, stream>>>(qtbl, S_glob, Emax, V);
  k_chain<<<dim3(N), dim3(64), 0, stream>>>(x, start_w, start_b, Tcol, qtbl, chainLL);
  k_emaxsum<<<dim3(128), dim3(256), 0, stream>>>(x, Emax, sumE, NT);
  k_final<<<dim3(1), dim3(64), 0, stream>>>(chainLL, sumE, (float*)d_out, N);
}

// Round 3
// 2031.048 us; speedup vs baseline: 1.4193x; 1.4193x over previous
//
#include <hip/hip_runtime.h>

typedef unsigned int uint;
typedef uint4 uint4_a __attribute__((may_alias));

// ---------- bf16 helpers ----------
__device__ __forceinline__ uint bfpack(float a, float b) {
  uint ua = __float_as_uint(a), ub = __float_as_uint(b);
  ua += 0x7fffu + ((ua >> 16) & 1u);   // RNE to bf16
  ub += 0x7fffu + ((ub >> 16) & 1u);
  return (ua >> 16) | (ub & 0xffff0000u);
}
__device__ __forceinline__ float bflo(uint d) { return __uint_as_float(d << 16); }
__device__ __forceinline__ float bfhi(uint d) { return __uint_as_float(d & 0xffff0000u); }

#if __has_builtin(__builtin_amdgcn_fdot2_f32_bf16)
#define HAVE_BFDOT 1
typedef __bf16 v2bf __attribute__((ext_vector_type(2)));
__device__ __forceinline__ float dot2bf(uint a, uint b, float c) {
  return __builtin_amdgcn_fdot2_f32_bf16(__builtin_bit_cast(v2bf, a),
                                         __builtin_bit_cast(v2bf, b), c, false);
}
#else
#define HAVE_BFDOT 0
#endif

// ---------- K1: transition table ----------
// Tcol[c*64 + j] = bf16x2( exp(tran[2j][c]), exp(tran[2j+1][c]) ), tran = log_softmax rows
__global__ void k_tran(const float* __restrict__ w, uint* __restrict__ Tcol) {
  __shared__ float rowLSE[128];
  int tid = threadIdx.x;                       // 128 threads
  const float4* w4 = (const float4*)(w + tid * 128);
  float se = 0.f;
  #pragma unroll 8
  for (int i = 0; i < 32; ++i) {
    float4 v = w4[i];
    se += __expf(v.x) + __expf(v.y) + __expf(v.z) + __expf(v.w);
  }
  rowLSE[tid] = __logf(se);                    // logits in (-1,1): shift-free LSE is exact enough
  __syncthreads();
  int c = tid;
  for (int j = 0; j < 64; ++j) {
    float a = __expf(w[(2 * j) * 128 + c]     - rowLSE[2 * j]);
    float b = __expf(w[(2 * j + 1) * 128 + c] - rowLSE[2 * j + 1]);
    Tcol[c * 64 + j] = bfpack(a, b);
  }
}

// ---------- K2a: logits (bf16, pair layout) + per-k sum of exp(logit) ----------
__global__ __launch_bounds__(256) void k_logits(const float* __restrict__ emb,
    const float* __restrict__ vocab, uint* __restrict__ qtbl,
    float* __restrict__ S_glob, int V) {
  __shared__ float S_part[128];
  int tid = threadIdx.x;
  int kt = tid & 15, vt = tid >> 4;
  int k0 = kt * 8;
  int vbase = blockIdx.x * 64 + vt * 4;
  if (tid < 128) S_part[tid] = 0.f;
  __syncthreads();

  float acc[4][8];
  #pragma unroll
  for (int i = 0; i < 4; ++i)
    #pragma unroll
    for (int r = 0; r < 8; ++r) acc[i][r] = 0.f;

  int vidx[4];
  #pragma unroll
  for (int i = 0; i < 4; ++i) { int vv = vbase + i; vidx[i] = (vv < V) ? vv : (V - 1); }

  const float4* emb4 = (const float4*)emb;
  const float4* voc4 = (const float4*)vocab;
  for (int jb = 0; jb < 32; ++jb) {
    float4 e4[8];
    #pragma unroll
    for (int r = 0; r < 8; ++r) e4[r] = emb4[(k0 + r) * 32 + jb];
    #pragma unroll
    for (int i = 0; i < 4; ++i) {
      float4 va = voc4[(size_t)vidx[i] * 32 + jb];
      #pragma unroll
      for (int r = 0; r < 8; ++r)
        acc[i][r] += va.x * e4[r].x + va.y * e4[r].y + va.z * e4[r].z + va.w * e4[r].w;
    }
  }

  float sume[8];
  #pragma unroll
  for (int r = 0; r < 8; ++r) sume[r] = 0.f;
  #pragma unroll
  for (int i = 0; i < 4; ++i) {
    int vv = vbase + i;
    if (vv < V) {
      #pragma unroll
      for (int r = 0; r < 8; ++r) sume[r] += __expf(acc[i][r]);   // |logit| <~ 40 : safe
      uint4 st;
      st.x = bfpack(acc[i][0], acc[i][1]);
      st.y = bfpack(acc[i][2], acc[i][3]);
      st.z = bfpack(acc[i][4], acc[i][5]);
      st.w = bfpack(acc[i][6], acc[i][7]);
      *((uint4*)(qtbl + (size_t)vv * 64) + kt) = st;
    }
  }
  #pragma unroll
  for (int r = 0; r < 8; ++r) atomicAdd(&S_part[k0 + r], sume[r]);
  __syncthreads();
  if (tid < 128) atomicAdd(&S_glob[tid], S_part[tid]);
}

// ---------- K2c: in-place q[v][k] = exp(emis - Emax_v) (bf16), Emax table ----------
__global__ __launch_bounds__(256) void k_qtab(uint* __restrict__ qtbl,
    const float* __restrict__ S_glob, float* __restrict__ Emax, int V) {
  int tid = threadIdx.x;
  int l = tid & 63;
  int v = blockIdx.x * 4 + (tid >> 6);
  if (v >= V) return;
  float2 S2 = ((const float2*)S_glob)[l];
  float z0 = __logf(S2.x), z1 = __logf(S2.y);
  size_t off = (size_t)v * 64 + l;
  uint d = qtbl[off];
  float e0 = bflo(d) - z0, e1 = bfhi(d) - z1;
  float m = fmaxf(e0, e1);
  #pragma unroll
  for (int s = 1; s < 64; s <<= 1) m = fmaxf(m, __shfl_xor(m, s, 64));
  float q0 = __expf(e0 - m), q1 = __expf(e1 - m);
  qtbl[off] = bfpack(q0, q1);
  if (l == 0) Emax[v] = m;
}

// ---------- K3: the sequential scan. One wave per chain. ----------
// Table held in 32 NAMED uint4 registers (no private arrays -> no scratch).

#if HAVE_BFDOT
#define DECL_T(i) uint4 tA##i, tB##i;
#define LOAD_T(i) tA##i = c0[i]; tB##i = c1[i];
#define DOT_I(i) { uint4 uu = u4[i]; \
  A0 = dot2bf(uu.x, tA##i.x, A0); B0 = dot2bf(uu.x, tB##i.x, B0); \
  A1 = dot2bf(uu.y, tA##i.y, A1); B1 = dot2bf(uu.y, tB##i.y, B1); \
  A2 = dot2bf(uu.z, tA##i.z, A2); B2 = dot2bf(uu.z, tB##i.z, B2); \
  A3 = dot2bf(uu.w, tA##i.w, A3); B3 = dot2bf(uu.w, tB##i.w, B3); }
#else
// NOTE: variant digit BEFORE pasted index (fA0_##i) — pasting a trailing
// digit next to ".x" lexes "1.x" as one pp-number and breaks.
#define DECL_T(i) float4 fA0_##i, fA1_##i, fB0_##i, fB1_##i;
#define LOAD_T(i) { uint4 a = c0[i], b = c1[i]; \
  fA0_##i = make_float4(bflo(a.x), bfhi(a.x), bflo(a.y), bfhi(a.y)); \
  fA1_##i = make_float4(bflo(a.z), bfhi(a.z), bflo(a.w), bfhi(a.w)); \
  fB0_##i = make_float4(bflo(b.x), bfhi(b.x), bflo(b.y), bfhi(b.y)); \
  fB1_##i = make_float4(bflo(b.z), bfhi(b.z), bflo(b.w), bfhi(b.w)); }
#define DOT_I(i) { uint4 uu = u4[i]; \
  float x0 = bflo(uu.x), x1 = bfhi(uu.x), x2 = bflo(uu.y), x3 = bfhi(uu.y); \
  float x4 = bflo(uu.z), x5 = bfhi(uu.z), x6 = bflo(uu.w), x7 = bfhi(uu.w); \
  A0 += x0 * fA0_##i.x; B0 += x0 * fB0_##i.x; \
  A1 += x1 * fA0_##i.y; B1 += x1 * fB0_##i.y; \
  A2 += x2 * fA0_##i.z; B2 += x2 * fB0_##i.z; \
  A3 += x3 * fA0_##i.w; B3 += x3 * fB0_##i.w; \
  A0 += x4 * fA1_##i.x; B0 += x4 * fB1_##i.x; \
  A1 += x5 * fA1_##i.y; B1 += x5 * fB1_##i.y; \
  A2 += x6 * fA1_##i.z; B2 += x6 * fB1_##i.z; \
  A3 += x7 * fA1_##i.w; B3 += x7 * fB1_##i.w; }
#endif

#define REP16(M) M(0) M(1) M(2) M(3) M(4) M(5) M(6) M(7) \
                 M(8) M(9) M(10) M(11) M(12) M(13) M(14) M(15)

#define STEP(j) { \
  float A0 = 0.f, A1 = 0.f, A2 = 0.f, A3 = 0.f; \
  float B0 = 0.f, B1 = 0.f, B2 = 0.f, B3 = 0.f; \
  REP16(DOT_I) \
  float s0 = (A0 + A1) + (A2 + A3); \
  float s1 = (B0 + B1) + (B2 + B3); \
  float nu0 = s0 * bflo(q##j), nu1 = s1 * bfhi(q##j); \
  q##j = qtbl[(size_t)xs[(tbase + j + 8) & 4095] * 64 + l];  /* prefetch 8 ahead */ \
  if (j == 7) {                                  /* exact renorm every 8 steps */ \
    float tt = nu0 + nu1; \
    for (int s = 1; s < 64; s <<= 1) tt += __shfl_xor(tt, s, 64); \
    LLacc += __logf(tt); \
    float it = 1.0f / tt; \
    nu0 *= it; nu1 *= it; \
  } \
  u_mem[l] = bfpack(nu0, nu1); }                 /* wave-lockstep: no barrier */

#define QINIT(j) uint q##j = qtbl[(size_t)xs[j] * 64 + l];

__global__ __launch_bounds__(64, 1) void k_chain(const int* __restrict__ x,
    const float* __restrict__ start_w, const float* __restrict__ start_b,
    const uint* __restrict__ Tcol, const uint* __restrict__ qtbl,
    float* __restrict__ chainLL) {
  __shared__ int xs[4096];
  __shared__ uint u_mem[64] __attribute__((aligned(16)));
  int n = blockIdx.x, l = threadIdx.x;
  const int* xrow = x + (size_t)n * 4096;
  #pragma unroll 4
  for (int i = l; i < 4096; i += 64) xs[i] = xrow[i];

  const uint4* c0 = (const uint4*)(Tcol + (2 * l) * 64);
  const uint4* c1 = (const uint4*)(Tcol + (2 * l + 1) * 64);
  REP16(DECL_T)
  REP16(LOAD_T)

  // init: u0 = softmax(start_w + start_b), LL0 = LSE(alpha0)
  float a0 = start_w[2 * l] + start_b[2 * l];
  float a1 = start_w[2 * l + 1] + start_b[2 * l + 1];
  float m = fmaxf(a0, a1);
  #pragma unroll
  for (int s = 1; s < 64; s <<= 1) m = fmaxf(m, __shfl_xor(m, s, 64));
  float p0 = __expf(a0 - m), p1 = __expf(a1 - m);
  float tot = p0 + p1;
  #pragma unroll
  for (int s = 1; s < 64; s <<= 1) tot += __shfl_xor(tot, s, 64);
  float LLacc = m + __logf(tot);
  float inv = 1.0f / tot;
  __syncthreads();
  u_mem[l] = bfpack(p0 * inv, p1 * inv);

  QINIT(0) QINIT(1) QINIT(2) QINIT(3) QINIT(4) QINIT(5) QINIT(6) QINIT(7)

  const uint4_a* u4 = (const uint4_a*)u_mem;
  for (int t8 = 0; t8 < 512; ++t8) {
    int tbase = t8 * 8;
    STEP(0) STEP(1) STEP(2) STEP(3) STEP(4) STEP(5) STEP(6) STEP(7)
  }
  if (l == 0) chainLL[n] = LLacc;
}

// ---------- K4a: sum of Emax over all tokens ----------
__global__ __launch_bounds__(256) void k_emaxsum(const int* __restrict__ x,
    const float* __restrict__ Emax, float* __restrict__ sumE, int NT) {
  int idx = blockIdx.x * 256 + threadIdx.x;
  float s = 0.f;
  for (; idx < NT; idx += 128 * 256) s += Emax[x[idx]];
  #pragma unroll
  for (int mk = 1; mk < 64; mk <<= 1) s += __shfl_xor(s, mk, 64);
  if ((threadIdx.x & 63) == 0) atomicAdd(sumE, s);
}

// ---------- K4b: final scalar ----------
__global__ void k_final(const float* __restrict__ chainLL, const float* __restrict__ sumE,
                        float* __restrict__ out, int N) {
  int l = threadIdx.x;
  float v = (l < N) ? chainLL[l] : 0.f;
  #pragma unroll
  for (int mk = 1; mk < 64; mk <<= 1) v += __shfl_xor(v, mk, 64);
  if (l == 0) out[0] = -(v + sumE[0]) / (float)N;
}

extern "C" void kernel_launch(void* const* d_in, const int* in_sizes, int n_in,
                              void* d_out, int out_size, void* d_ws, size_t ws_size,
                              hipStream_t stream) {
  if (n_in < 6) return;
  const int*   x       = (const int*)d_in[0];
  const float* start_w = (const float*)d_in[1];
  const float* start_b = (const float*)d_in[2];
  const float* trans_w = (const float*)d_in[3];
  const float* emb_w   = (const float*)d_in[4];
  const float* vocab_w = (const float*)d_in[5];
  int NT = in_sizes[0];
  int N  = NT / 4096;
  int V  = in_sizes[5] / 128;

  char* ws = (char*)d_ws;
  float* S_glob  = (float*)(ws + 0);        // 128 f
  float* sumE    = (float*)(ws + 512);      // 1 f
  float* chainLL = (float*)(ws + 768);      // N f
  uint*  Tcol    = (uint*)(ws + 1024);      // 128*64 dwords = 32 KB
  float* Emax    = (float*)(ws + 36864);    // V floats
  uint*  qtbl    = (uint*)(ws + 262144);    // V*64 dwords = 12.8 MB

  hipMemsetAsync(d_ws, 0, 1024, stream);
  k_tran<<<dim3(1), dim3(128), 0, stream>>>(trans_w, Tcol);
  k_logits<<<dim3((V + 63) / 64), dim3(256), 0, stream>>>(emb_w, vocab_w, qtbl, S_glob, V);
  k_qtab<<<dim3((V + 3) / 4), dim3(256), 0, stream>>>(qtbl, S_glob, Emax, V);
  k_chain<<<dim3(N), dim3(64), 0, stream>>>(x, start_w, start_b, Tcol, qtbl, chainLL);
  k_emaxsum<<<dim3(128), dim3(256), 0, stream>>>(x, Emax, sumE, NT);
  k_final<<<dim3(1), dim3(64), 0, stream>>>(chainLL, sumE, (float*)d_out, N);
}

// Round 4
// 1657.170 us; speedup vs baseline: 1.7395x; 1.2256x over previous
//
#include <hip/hip_runtime.h>

typedef unsigned int uint;

// ---------- bf16 helpers ----------
__device__ __forceinline__ uint bfpack(float a, float b) {
  uint ua = __float_as_uint(a), ub = __float_as_uint(b);
  ua += 0x7fffu + ((ua >> 16) & 1u);   // RNE to bf16
  ub += 0x7fffu + ((ub >> 16) & 1u);
  return (ua >> 16) | (ub & 0xffff0000u);
}
__device__ __forceinline__ float bflo(uint d) { return __uint_as_float(d << 16); }
__device__ __forceinline__ float bfhi(uint d) { return __uint_as_float(d & 0xffff0000u); }

#if __has_builtin(__builtin_amdgcn_fdot2_f32_bf16)
#define HAVE_BFDOT 1
typedef __bf16 v2bf __attribute__((ext_vector_type(2)));
__device__ __forceinline__ float dot2bf(uint a, uint b, float c) {
  return __builtin_amdgcn_fdot2_f32_bf16(__builtin_bit_cast(v2bf, a),
                                         __builtin_bit_cast(v2bf, b), c, false);
}
#else
#define HAVE_BFDOT 0
#endif

// ---------- K1: transition table ----------
// Tcol[c*64 + j] = bf16x2( exp(tran[2j][c]), exp(tran[2j+1][c]) ), tran = log_softmax rows
__global__ void k_tran(const float* __restrict__ w, uint* __restrict__ Tcol) {
  __shared__ float rowLSE[128];
  int tid = threadIdx.x;                       // 128 threads
  const float4* w4 = (const float4*)(w + tid * 128);
  float se = 0.f;
  #pragma unroll 8
  for (int i = 0; i < 32; ++i) {
    float4 v = w4[i];
    se += __expf(v.x) + __expf(v.y) + __expf(v.z) + __expf(v.w);
  }
  rowLSE[tid] = __logf(se);                    // logits in (-1,1): shift-free LSE is fine
  __syncthreads();
  int c = tid;
  for (int j = 0; j < 64; ++j) {
    float a = __expf(w[(2 * j) * 128 + c]     - rowLSE[2 * j]);
    float b = __expf(w[(2 * j + 1) * 128 + c] - rowLSE[2 * j + 1]);
    Tcol[c * 64 + j] = bfpack(a, b);
  }
}

// ---------- K2a: logits (bf16, pair layout) + per-k sum of exp(logit) ----------
__global__ __launch_bounds__(256) void k_logits(const float* __restrict__ emb,
    const float* __restrict__ vocab, uint* __restrict__ qtbl,
    float* __restrict__ S_glob, int V) {
  __shared__ float S_part[128];
  int tid = threadIdx.x;
  int kt = tid & 15, vt = tid >> 4;
  int k0 = kt * 8;
  int vbase = blockIdx.x * 64 + vt * 4;
  if (tid < 128) S_part[tid] = 0.f;
  __syncthreads();

  float acc[4][8];
  #pragma unroll
  for (int i = 0; i < 4; ++i)
    #pragma unroll
    for (int r = 0; r < 8; ++r) acc[i][r] = 0.f;

  int vidx[4];
  #pragma unroll
  for (int i = 0; i < 4; ++i) { int vv = vbase + i; vidx[i] = (vv < V) ? vv : (V - 1); }

  const float4* emb4 = (const float4*)emb;
  const float4* voc4 = (const float4*)vocab;
  for (int jb = 0; jb < 32; ++jb) {
    float4 e4[8];
    #pragma unroll
    for (int r = 0; r < 8; ++r) e4[r] = emb4[(k0 + r) * 32 + jb];
    #pragma unroll
    for (int i = 0; i < 4; ++i) {
      float4 va = voc4[(size_t)vidx[i] * 32 + jb];
      #pragma unroll
      for (int r = 0; r < 8; ++r)
        acc[i][r] += va.x * e4[r].x + va.y * e4[r].y + va.z * e4[r].z + va.w * e4[r].w;
    }
  }

  float sume[8];
  #pragma unroll
  for (int r = 0; r < 8; ++r) sume[r] = 0.f;
  #pragma unroll
  for (int i = 0; i < 4; ++i) {
    int vv = vbase + i;
    if (vv < V) {
      #pragma unroll
      for (int r = 0; r < 8; ++r) sume[r] += __expf(acc[i][r]);   // |logit| <~ 40 : safe
      uint4 st;
      st.x = bfpack(acc[i][0], acc[i][1]);
      st.y = bfpack(acc[i][2], acc[i][3]);
      st.z = bfpack(acc[i][4], acc[i][5]);
      st.w = bfpack(acc[i][6], acc[i][7]);
      *((uint4*)(qtbl + (size_t)vv * 64) + kt) = st;
    }
  }
  #pragma unroll
  for (int r = 0; r < 8; ++r) atomicAdd(&S_part[k0 + r], sume[r]);
  __syncthreads();
  if (tid < 128) atomicAdd(&S_glob[tid], S_part[tid]);
}

// ---------- K2c: in-place q[v][k] = exp(emis - Emax_v) (bf16), Emax table ----------
__global__ __launch_bounds__(256) void k_qtab(uint* __restrict__ qtbl,
    const float* __restrict__ S_glob, float* __restrict__ Emax, int V) {
  int tid = threadIdx.x;
  int l = tid & 63;
  int v = blockIdx.x * 4 + (tid >> 6);
  if (v >= V) return;
  float2 S2 = ((const float2*)S_glob)[l];
  float z0 = __logf(S2.x), z1 = __logf(S2.y);
  size_t off = (size_t)v * 64 + l;
  uint d = qtbl[off];
  float e0 = bflo(d) - z0, e1 = bfhi(d) - z1;
  float m = fmaxf(e0, e1);
  #pragma unroll
  for (int s = 1; s < 64; s <<= 1) m = fmaxf(m, __shfl_xor(m, s, 64));
  float q0 = __expf(e0 - m), q1 = __expf(e1 - m);
  qtbl[off] = bfpack(q0, q1);
  if (l == 0) Emax[v] = m;
}

// ---------- K3: sequential scan. 4 waves per chain, K split across waves. ----------
// Wave w owns input states [32w,32w+32) = u-dwords [16w,16w+16), fetched from the
// wave's own packed-u register via v_readlane (u never goes through LDS).
// Per-lane table: 4+4 uint4 (outputs 2l,2l+1 x 16 input-pairs) -> no spill possible.
// Cross-wave partial sums: double-buffered LDS (stride 10 dwords: conflict-free),
// one raw s_barrier per step (manual lgkmcnt(0); NO vmcnt drain -> q prefetch lives).

#define RLU(i) ((uint)__builtin_amdgcn_readlane((int)ud, rbase + (i)))

#if HAVE_BFDOT
#define DOTS \
  uint u0=RLU(0),u1=RLU(1),u2=RLU(2),u3=RLU(3),u4=RLU(4),u5=RLU(5),u6=RLU(6),u7=RLU(7), \
       u8=RLU(8),u9=RLU(9),u10=RLU(10),u11=RLU(11),u12=RLU(12),u13=RLU(13),u14=RLU(14),u15=RLU(15); \
  float A0 = dot2bf(u0, tA0.x, 0.f), A1 = dot2bf(u1, tA0.y, 0.f); \
  float A2 = dot2bf(u2, tA0.z, 0.f), A3 = dot2bf(u3, tA0.w, 0.f); \
  float B0 = dot2bf(u0, tB0.x, 0.f), B1 = dot2bf(u1, tB0.y, 0.f); \
  float B2 = dot2bf(u2, tB0.z, 0.f), B3 = dot2bf(u3, tB0.w, 0.f); \
  A0 = dot2bf(u4, tA1.x, A0); A1 = dot2bf(u5, tA1.y, A1); \
  A2 = dot2bf(u6, tA1.z, A2); A3 = dot2bf(u7, tA1.w, A3); \
  B0 = dot2bf(u4, tB1.x, B0); B1 = dot2bf(u5, tB1.y, B1); \
  B2 = dot2bf(u6, tB1.z, B2); B3 = dot2bf(u7, tB1.w, B3); \
  A0 = dot2bf(u8, tA2.x, A0); A1 = dot2bf(u9, tA2.y, A1); \
  A2 = dot2bf(u10, tA2.z, A2); A3 = dot2bf(u11, tA2.w, A3); \
  B0 = dot2bf(u8, tB2.x, B0); B1 = dot2bf(u9, tB2.y, B1); \
  B2 = dot2bf(u10, tB2.z, B2); B3 = dot2bf(u11, tB2.w, B3); \
  A0 = dot2bf(u12, tA3.x, A0); A1 = dot2bf(u13, tA3.y, A1); \
  A2 = dot2bf(u14, tA3.z, A2); A3 = dot2bf(u15, tA3.w, A3); \
  B0 = dot2bf(u12, tB3.x, B0); B1 = dot2bf(u13, tB3.y, B1); \
  B2 = dot2bf(u14, tB3.z, B2); B3 = dot2bf(u15, tB3.w, B3); \
  float Asum = (A0 + A1) + (A2 + A3), Bsum = (B0 + B1) + (B2 + B3);
#else
// u value is wave-uniform (readlane) -> unpack stays on SALU; one SGPR/VALU op ok.
#define ACC2(i, AA, BB) { uint tu = RLU(i); float lo = bflo(tu), hi = bfhi(tu); \
  AA += lo * a##i.x; AA += hi * a##i.y; BB += lo * b##i.x; BB += hi * b##i.y; }
#define DOTS \
  float A0 = 0.f, A1 = 0.f, A2 = 0.f, A3 = 0.f; \
  float B0 = 0.f, B1 = 0.f, B2 = 0.f, B3 = 0.f; \
  ACC2(0, A0, B0) ACC2(1, A1, B1) ACC2(2, A2, B2) ACC2(3, A3, B3) \
  ACC2(4, A0, B0) ACC2(5, A1, B1) ACC2(6, A2, B2) ACC2(7, A3, B3) \
  ACC2(8, A0, B0) ACC2(9, A1, B1) ACC2(10, A2, B2) ACC2(11, A3, B3) \
  ACC2(12, A0, B0) ACC2(13, A1, B1) ACC2(14, A2, B2) ACC2(15, A3, B3) \
  float Asum = (A0 + A1) + (A2 + A3), Bsum = (B0 + B1) + (B2 + B3);
#endif

// p must be a literal 0/1: part buffer offset folded at compile time.
#define STEP(j, p) { \
  DOTS \
  *(float2*)&partLDS[(p) * 640 + l * 10 + 2 * wv] = make_float2(Asum, Bsum); \
  asm volatile("s_waitcnt lgkmcnt(0)\ns_barrier" ::: "memory"); \
  const float2* pr = (const float2*)&partLDS[(p) * 640 + l * 10]; \
  float2 x0 = pr[0], x1 = pr[1], x2 = pr[2], x3 = pr[3]; \
  float s0 = (x0.x + x1.x) + (x2.x + x3.x); \
  float s1 = (x0.y + x1.y) + (x2.y + x3.y); \
  float nu0 = s0 * bflo(qc##j), nu1 = s1 * bfhi(qc##j); \
  { int tok = xrow[(tbase + j + 8) & 4095]; qc##j = qtbl[(size_t)tok * 64 + l]; } \
  if ((j) == 7) {                                 /* exact renorm every 8 steps */ \
    float tt = nu0 + nu1; \
    for (int s = 1; s < 64; s <<= 1) tt += __shfl_xor(tt, s, 64); \
    LLacc += __logf(tt); \
    float it = 1.0f / tt; nu0 *= it; nu1 *= it; \
  } \
  ud = bfpack(nu0, nu1); }

__global__ __launch_bounds__(256, 1) void k_chain(const int* __restrict__ x,
    const float* __restrict__ start_w, const float* __restrict__ start_b,
    const uint* __restrict__ Tcol, const uint* __restrict__ qtbl,
    float* __restrict__ chainLL) {
  __shared__ float partLDS[1280];                 // [2][64 lanes x 10 dwords] = 5 KB
  int n = blockIdx.x;
  int l = threadIdx.x & 63;
  int wv = __builtin_amdgcn_readfirstlane((int)(threadIdx.x >> 6));  // force SGPR
  int rbase = wv * 16;
  const int* xrow = x + (size_t)n * 4096;

  // per-lane table fragment: columns 2l, 2l+1; input pairs [16wv, 16wv+16)
  const uint4* ca = (const uint4*)(Tcol + (2 * l) * 64 + rbase);
  const uint4* cb = (const uint4*)(Tcol + (2 * l + 1) * 64 + rbase);
  uint4 tA0 = ca[0], tA1 = ca[1], tA2 = ca[2], tA3 = ca[3];
  uint4 tB0 = cb[0], tB1 = cb[1], tB2 = cb[2], tB3 = cb[3];

#if !HAVE_BFDOT
  float2 a0 = make_float2(bflo(tA0.x), bfhi(tA0.x)), a1 = make_float2(bflo(tA0.y), bfhi(tA0.y));
  float2 a2 = make_float2(bflo(tA0.z), bfhi(tA0.z)), a3 = make_float2(bflo(tA0.w), bfhi(tA0.w));
  float2 a4 = make_float2(bflo(tA1.x), bfhi(tA1.x)), a5 = make_float2(bflo(tA1.y), bfhi(tA1.y));
  float2 a6 = make_float2(bflo(tA1.z), bfhi(tA1.z)), a7 = make_float2(bflo(tA1.w), bfhi(tA1.w));
  float2 a8 = make_float2(bflo(tA2.x), bfhi(tA2.x)), a9 = make_float2(bflo(tA2.y), bfhi(tA2.y));
  float2 a10 = make_float2(bflo(tA2.z), bfhi(tA2.z)), a11 = make_float2(bflo(tA2.w), bfhi(tA2.w));
  float2 a12 = make_float2(bflo(tA3.x), bfhi(tA3.x)), a13 = make_float2(bflo(tA3.y), bfhi(tA3.y));
  float2 a14 = make_float2(bflo(tA3.z), bfhi(tA3.z)), a15 = make_float2(bflo(tA3.w), bfhi(tA3.w));
  float2 b0 = make_float2(bflo(tB0.x), bfhi(tB0.x)), b1 = make_float2(bflo(tB0.y), bfhi(tB0.y));
  float2 b2 = make_float2(bflo(tB0.z), bfhi(tB0.z)), b3 = make_float2(bflo(tB0.w), bfhi(tB0.w));
  float2 b4 = make_float2(bflo(tB1.x), bfhi(tB1.x)), b5 = make_float2(bflo(tB1.y), bfhi(tB1.y));
  float2 b6 = make_float2(bflo(tB1.z), bfhi(tB1.z)), b7 = make_float2(bflo(tB1.w), bfhi(tB1.w));
  float2 b8 = make_float2(bflo(tB2.x), bfhi(tB2.x)), b9 = make_float2(bflo(tB2.y), bfhi(tB2.y));
  float2 b10 = make_float2(bflo(tB2.z), bfhi(tB2.z)), b11 = make_float2(bflo(tB2.w), bfhi(tB2.w));
  float2 b12 = make_float2(bflo(tB3.x), bfhi(tB3.x)), b13 = make_float2(bflo(tB3.y), bfhi(tB3.y));
  float2 b14 = make_float2(bflo(tB3.z), bfhi(tB3.z)), b15 = make_float2(bflo(tB3.w), bfhi(tB3.w));
#endif

  // init: u0 = softmax(start_w + start_b), LL0 = LSE(alpha0). Identical in all waves.
  float a0i = start_w[2 * l] + start_b[2 * l];
  float a1i = start_w[2 * l + 1] + start_b[2 * l + 1];
  float m = fmaxf(a0i, a1i);
  #pragma unroll
  for (int s = 1; s < 64; s <<= 1) m = fmaxf(m, __shfl_xor(m, s, 64));
  float p0 = __expf(a0i - m), p1 = __expf(a1i - m);
  float tot = p0 + p1;
  #pragma unroll
  for (int s = 1; s < 64; s <<= 1) tot += __shfl_xor(tot, s, 64);
  float LLacc = m + __logf(tot);
  float inv = 1.0f / tot;
  uint ud = bfpack(p0 * inv, p1 * inv);           // packed u(2l,2l+1), lives in a VGPR

  uint qc0 = qtbl[(size_t)xrow[0] * 64 + l], qc1 = qtbl[(size_t)xrow[1] * 64 + l];
  uint qc2 = qtbl[(size_t)xrow[2] * 64 + l], qc3 = qtbl[(size_t)xrow[3] * 64 + l];
  uint qc4 = qtbl[(size_t)xrow[4] * 64 + l], qc5 = qtbl[(size_t)xrow[5] * 64 + l];
  uint qc6 = qtbl[(size_t)xrow[6] * 64 + l], qc7 = qtbl[(size_t)xrow[7] * 64 + l];

  for (int t8 = 0; t8 < 512; ++t8) {
    int tbase = t8 * 8;
    STEP(0, 0) STEP(1, 1) STEP(2, 0) STEP(3, 1)
    STEP(4, 0) STEP(5, 1) STEP(6, 0) STEP(7, 1)
  }
  if (l == 0 && wv == 0) chainLL[n] = LLacc;
}

// ---------- K4a: sum of Emax over all tokens ----------
__global__ __launch_bounds__(256) void k_emaxsum(const int* __restrict__ x,
    const float* __restrict__ Emax, float* __restrict__ sumE, int NT) {
  int idx = blockIdx.x * 256 + threadIdx.x;
  float s = 0.f;
  for (; idx < NT; idx += 128 * 256) s += Emax[x[idx]];
  #pragma unroll
  for (int mk = 1; mk < 64; mk <<= 1) s += __shfl_xor(s, mk, 64);
  if ((threadIdx.x & 63) == 0) atomicAdd(sumE, s);
}

// ---------- K4b: final scalar ----------
__global__ void k_final(const float* __restrict__ chainLL, const float* __restrict__ sumE,
                        float* __restrict__ out, int N) {
  int l = threadIdx.x;
  float v = (l < N) ? chainLL[l] : 0.f;
  #pragma unroll
  for (int mk = 1; mk < 64; mk <<= 1) v += __shfl_xor(v, mk, 64);
  if (l == 0) out[0] = -(v + sumE[0]) / (float)N;
}

extern "C" void kernel_launch(void* const* d_in, const int* in_sizes, int n_in,
                              void* d_out, int out_size, void* d_ws, size_t ws_size,
                              hipStream_t stream) {
  if (n_in < 6) return;
  const int*   x       = (const int*)d_in[0];
  const float* start_w = (const float*)d_in[1];
  const float* start_b = (const float*)d_in[2];
  const float* trans_w = (const float*)d_in[3];
  const float* emb_w   = (const float*)d_in[4];
  const float* vocab_w = (const float*)d_in[5];
  int NT = in_sizes[0];
  int N  = NT / 4096;
  int V  = in_sizes[5] / 128;

  char* ws = (char*)d_ws;
  float* S_glob  = (float*)(ws + 0);        // 128 f
  float* sumE    = (float*)(ws + 512);      // 1 f
  float* chainLL = (float*)(ws + 768);      // N f
  uint*  Tcol    = (uint*)(ws + 1024);      // 128*64 dwords = 32 KB
  float* Emax    = (float*)(ws + 36864);    // V floats
  uint*  qtbl    = (uint*)(ws + 262144);    // V*64 dwords = 12.8 MB

  hipMemsetAsync(d_ws, 0, 1024, stream);
  k_tran<<<dim3(1), dim3(128), 0, stream>>>(trans_w, Tcol);
  k_logits<<<dim3((V + 63) / 64), dim3(256), 0, stream>>>(emb_w, vocab_w, qtbl, S_glob, V);
  k_qtab<<<dim3((V + 3) / 4), dim3(256), 0, stream>>>(qtbl, S_glob, Emax, V);
  k_chain<<<dim3(N), dim3(256), 0, stream>>>(x, start_w, start_b, Tcol, qtbl, chainLL);
  k_emaxsum<<<dim3(128), dim3(256), 0, stream>>>(x, Emax, sumE, NT);
  k_final<<<dim3(1), dim3(64), 0, stream>>>(chainLL, sumE, (float*)d_out, N);
}